// Round 1
// baseline (1158.316 us; speedup 1.0000x reference)
//
#include <hip/hip_runtime.h>
#include <hip/hip_bf16.h>
#include <stdint.h>

#define T_SEQ 500
#define D_IN  32
#define H_DIM 64
#define ROWS  16     // batch rows per block (one 16-row M-tile)
#define BDIM  256    // 4 waves

using short8  = __attribute__((ext_vector_type(8))) short;  // 8 bf16 (4 VGPRs)
using float4_ = __attribute__((ext_vector_type(4))) float;  // MFMA C/D frag

// split fp32 -> bf16 hi + bf16 lo (truncation; residual captured by lo, net ~2^-16 rel)
__device__ __forceinline__ void split_bf16(float v, unsigned short &hi, unsigned short &lo) {
    unsigned int b = __float_as_uint(v);
    hi = (unsigned short)(b >> 16);
    float vh = __uint_as_float(b & 0xFFFF0000u);
    lo = (unsigned short)(__float_as_uint(v - vh) >> 16);
}

__device__ __forceinline__ float fast_sigmoid(float x) {
    return __builtin_amdgcn_rcpf(1.0f + __expf(-x));           // exp: v_mul+v_exp, rcp: v_rcp
}
__device__ __forceinline__ float fast_tanh(float x) {
    return 1.0f - 2.0f * __builtin_amdgcn_rcpf(1.0f + __expf(2.0f * x));
}

// LDS A-buffer: [buf(2)][hi/lo(2)][ktile(3)][kgroup(4)][row(16)] of short8 (8 bf16, k-contig)
// k-map: element j of lane l  <->  k = (l>>4)*8 + j  (used consistently for A AND B frags)
__device__ __forceinline__ int frag_idx(int buf, int hl, int kt, int g, int row) {
    return (((buf * 2 + hl) * 3 + kt) * 4 + g) * 16 + row;
}

extern "C" __global__ void __launch_bounds__(BDIM, 1)
seq2seq_kernel(const float* __restrict__ x,
               const float* __restrict__ Wih_e, const float* __restrict__ Whh_e,
               const float* __restrict__ b_e,
               const float* __restrict__ Wih_d, const float* __restrict__ Whh_d,
               const float* __restrict__ b_d,
               const float* __restrict__ Wout, const float* __restrict__ bout,
               float* __restrict__ out)
{
    __shared__ short8 abuf[2 * 2 * 3 * 4 * 16];   // 12 KB
    unsigned short* au = reinterpret_cast<unsigned short*>(abuf);

    const int tid  = threadIdx.x;
    const int wave = tid >> 6;
    const int lane = tid & 63;
    const int rg   = lane >> 4;          // lane k-group (A/B) == row-group (C/D)
    const int lcol = lane & 15;          // A: M-row | B,C/D: N-col
    const int unit = wave * 16 + lcol;   // hidden unit owned by this lane (0..63)
    const int row0 = blockIdx.x * ROWS;

    // LDS position of h[unit] in the A-buffer: global k = 32 + unit
    const int kt_h = 1 + (unit >> 5);
    const int u5   = unit & 31;
    const int g_h  = u5 >> 3;
    const int j_h  = u5 & 7;

    // ---- gate weight fragments in registers (hi+lo split); wave w's N-tiles are
    // cols {0,64,128,192}+16w  => lane's col n = nt*64 + unit; k = kt*32 + rg*8 + j ----
    short8 whi[3][4], wlo[3][4];
    float  bv[4];
    #pragma unroll
    for (int nt = 0; nt < 4; ++nt) {
        const int n = nt * 64 + unit;
        bv[nt] = b_e[n];
        #pragma unroll
        for (int kt = 0; kt < 3; ++kt) {
            const int k0 = kt * 32 + rg * 8;
            const float* src = (k0 < 32) ? (Wih_e + n * D_IN + k0)
                                         : (Whh_e + n * H_DIM + (k0 - 32));
            #pragma unroll
            for (int j = 0; j < 8; ++j) {
                unsigned short h, l;
                split_bf16(src[j], h, l);
                whi[kt][nt][j] = (short)h;
                wlo[kt][nt][j] = (short)l;
            }
        }
    }

    short8 wohi[2], wolo[2];             // Wout frags (waves 0,1; loaded at phase switch)
    float  bo = 0.0f;
    const int ocol = (wave & 1) * 16 + lcol;

    float c4[4] = {0.f, 0.f, 0.f, 0.f};  // persistent cell state: rows rg*4+r, col=unit

    // ---- init buffer 0: zero h region (h0=0), stage x[:,0,:] ----
    {
        const int hl  = tid >> 7;
        const int rem = tid & 127;
        const int kt  = 1 + (rem >> 6);
        const int g   = (rem >> 4) & 3;
        const int row = rem & 15;
        short8 z = {0,0,0,0,0,0,0,0};
        abuf[frag_idx(0, hl, kt, g, row)] = z;
    }
    {
        const int row = tid >> 4;
        const int kp  = (tid & 15) * 2;
        const float2 v = *reinterpret_cast<const float2*>(
            x + ((size_t)(row0 + row) * T_SEQ + 0) * D_IN + kp);
        unsigned short h0, l0, h1, l1;
        split_bf16(v.x, h0, l0);
        split_bf16(v.y, h1, l1);
        const int g = kp >> 3, j = kp & 7;
        au[frag_idx(0, 0, 0, g, row) * 8 + j]     = h0;
        au[frag_idx(0, 0, 0, g, row) * 8 + j + 1] = h1;
        au[frag_idx(0, 1, 0, g, row) * 8 + j]     = l0;
        au[frag_idx(0, 1, 0, g, row) * 8 + j + 1] = l1;
    }
    __syncthreads();

    int cur = 0;
    for (int t = 0; t < 2 * T_SEQ; ++t) {
        if (t == T_SEQ) {   // ---- phase switch: load decoder weights ----
            #pragma unroll
            for (int nt = 0; nt < 4; ++nt) {
                const int n = nt * 64 + unit;
                bv[nt] = b_d[n];
                #pragma unroll
                for (int kt = 0; kt < 3; ++kt) {
                    const int k0 = kt * 32 + rg * 8;
                    const float* src = (k0 < 32) ? (Wih_d + n * D_IN + k0)
                                                 : (Whh_d + n * H_DIM + (k0 - 32));
                    #pragma unroll
                    for (int j = 0; j < 8; ++j) {
                        unsigned short h, l;
                        split_bf16(src[j], h, l);
                        whi[kt][nt][j] = (short)h;
                        wlo[kt][nt][j] = (short)l;
                    }
                }
            }
            if (wave < 2) {
                bo = bout[ocol];
                #pragma unroll
                for (int kt = 0; kt < 2; ++kt) {
                    const float* src = Wout + (size_t)ocol * H_DIM + kt * 32 + rg * 8;
                    #pragma unroll
                    for (int j = 0; j < 8; ++j) {
                        unsigned short h, l;
                        split_bf16(src[j], h, l);
                        wohi[kt][j] = (short)h;
                        wolo[kt][j] = (short)l;
                    }
                }
            }
        }

        const int nxt = cur ^ 1;

        // A fragments (hi/lo) for this step from LDS[cur]
        short8 ah[3], al[3];
        #pragma unroll
        for (int kt = 0; kt < 3; ++kt) {
            ah[kt] = abuf[frag_idx(cur, 0, kt, rg, lcol)];
            al[kt] = abuf[frag_idx(cur, 1, kt, rg, lcol)];
        }

        // early-issue next-step x load (encoder only; t==T_SEQ-1 stages zeros)
        float vx = 0.f, vy = 0.f;
        const int xrow = tid >> 4;
        const int xkp  = (tid & 15) * 2;
        if (t + 1 < T_SEQ) {
            const float2 v = *reinterpret_cast<const float2*>(
                x + ((size_t)(row0 + xrow) * T_SEQ + (t + 1)) * D_IN + xkp);
            vx = v.x; vy = v.y;
        }

        // ---- gate GEMM: acc = bias + A_hi*B_hi + A_hi*B_lo + A_lo*B_hi ----
        float4_ acc[4];
        #pragma unroll
        for (int nt = 0; nt < 4; ++nt) {
            float4_ a = {bv[nt], bv[nt], bv[nt], bv[nt]};
            acc[nt] = a;
        }
        #pragma unroll
        for (int nt = 0; nt < 4; ++nt) {
            #pragma unroll
            for (int kt = 0; kt < 3; ++kt) {
                acc[nt] = __builtin_amdgcn_mfma_f32_16x16x32_bf16(ah[kt], whi[kt][nt], acc[nt], 0, 0, 0);
                acc[nt] = __builtin_amdgcn_mfma_f32_16x16x32_bf16(ah[kt], wlo[kt][nt], acc[nt], 0, 0, 0);
                acc[nt] = __builtin_amdgcn_mfma_f32_16x16x32_bf16(al[kt], whi[kt][nt], acc[nt], 0, 0, 0);
            }
        }

        // ---- LSTM pointwise (fp32) + write split-bf16 h into LDS[nxt] ----
        #pragma unroll
        for (int r = 0; r < 4; ++r) {
            const float iv = fast_sigmoid(acc[0][r]);
            const float fv = fast_sigmoid(acc[1][r]);
            const float gv = fast_tanh(acc[2][r]);
            const float ov = fast_sigmoid(acc[3][r]);
            const float cv = fv * c4[r] + iv * gv;
            c4[r] = cv;
            const float hv = ov * fast_tanh(cv);
            unsigned short hh, hl2;
            split_bf16(hv, hh, hl2);
            const int row = rg * 4 + r;
            au[frag_idx(nxt, 0, kt_h, g_h, row) * 8 + j_h] = hh;
            au[frag_idx(nxt, 1, kt_h, g_h, row) * 8 + j_h] = hl2;
        }

        if (t < T_SEQ) {
            // encoder: stage x[t+1] (or zeros -> decoder's first input) into LDS[nxt]
            unsigned short h0, l0, h1, l1;
            split_bf16(vx, h0, l0);
            split_bf16(vy, h1, l1);
            const int g = xkp >> 3, j = xkp & 7;
            au[frag_idx(nxt, 0, 0, g, xrow) * 8 + j]     = h0;
            au[frag_idx(nxt, 0, 0, g, xrow) * 8 + j + 1] = h1;
            au[frag_idx(nxt, 1, 0, g, xrow) * 8 + j]     = l0;
            au[frag_idx(nxt, 1, 0, g, xrow) * 8 + j + 1] = l1;
            __syncthreads();
        } else {
            __syncthreads();   // new h visible in LDS[nxt]
            if (wave < 2) {
                // out = h_new @ Wout^T + bout  (waves 0/1 each own one 16-col N-tile)
                const int td = t - T_SEQ;
                short8 ah2[2], al2[2];
                #pragma unroll
                for (int kt = 0; kt < 2; ++kt) {
                    ah2[kt] = abuf[frag_idx(nxt, 0, 1 + kt, rg, lcol)];
                    al2[kt] = abuf[frag_idx(nxt, 1, 1 + kt, rg, lcol)];
                }
                float4_ oacc = {bo, bo, bo, bo};
                #pragma unroll
                for (int kt = 0; kt < 2; ++kt) {
                    oacc = __builtin_amdgcn_mfma_f32_16x16x32_bf16(ah2[kt], wohi[kt], oacc, 0, 0, 0);
                    oacc = __builtin_amdgcn_mfma_f32_16x16x32_bf16(ah2[kt], wolo[kt], oacc, 0, 0, 0);
                    oacc = __builtin_amdgcn_mfma_f32_16x16x32_bf16(al2[kt], wohi[kt], oacc, 0, 0, 0);
                }
                #pragma unroll
                for (int r = 0; r < 4; ++r) {
                    const int row = rg * 4 + r;
                    out[((size_t)(row0 + row) * T_SEQ + td) * D_IN + ocol] = oacc[r];
                    unsigned short hh, ll;
                    split_bf16(oacc[r], hh, ll);
                    const int g = ocol >> 3, j = ocol & 7;
                    au[frag_idx(nxt, 0, 0, g, row) * 8 + j] = hh;   // feedback input
                    au[frag_idx(nxt, 1, 0, g, row) * 8 + j] = ll;
                }
            }
            __syncthreads();
        }
        cur = nxt;
    }
}

extern "C" void kernel_launch(void* const* d_in, const int* in_sizes, int n_in,
                              void* d_out, int out_size, void* d_ws, size_t ws_size,
                              hipStream_t stream) {
    (void)n_in; (void)d_ws; (void)ws_size; (void)out_size;
    const float* x     = (const float*)d_in[0];
    const float* Wih_e = (const float*)d_in[1];
    const float* Whh_e = (const float*)d_in[2];
    const float* b_e   = (const float*)d_in[3];
    const float* Wih_d = (const float*)d_in[4];
    const float* Whh_d = (const float*)d_in[5];
    const float* b_d   = (const float*)d_in[6];
    const float* Wout  = (const float*)d_in[7];
    const float* bout  = (const float*)d_in[8];
    float* out = (float*)d_out;

    const int B = in_sizes[0] / (T_SEQ * D_IN);   // 4096
    dim3 grid(B / ROWS), block(BDIM);
    hipLaunchKernelGGL(seq2seq_kernel, grid, block, 0, stream,
                       x, Wih_e, Whh_e, b_e, Wih_d, Whh_d, b_d, Wout, bout, out);
}

// Round 2
// 849.093 us; speedup vs baseline: 1.3642x; 1.3642x over previous
//
#include <hip/hip_runtime.h>
#include <stdint.h>

#define T_SEQ 500
#define D_IN  32
#define H_DIM 64
#define ROWS  16
#define BDIM  256

using short8  = __attribute__((ext_vector_type(8))) short;  // 8 bf16
using float4_ = __attribute__((ext_vector_type(4))) float;  // MFMA C/D frag

// ---- LDS geometry (bytes). Frag block = 16 rows x 16B + 16B pad (bank de-alias) ----
#define FRAG_BLK      272
#define H_BUF_STRIDE  (16 * FRAG_BLK)   // hl(2) x kt(2) x g(4) = 16 blocks = 4352 B
#define X_SLOT_STRIDE (8 * FRAG_BLK)    // hl(2) x g(4) = 8 blocks = 2176 B
#define X_BASE        (2 * H_BUF_STRIDE)              // 8704
#define LDS_BYTES     (X_BASE + 2 * X_SLOT_STRIDE)    // 13056

__device__ __forceinline__ int h_off(int buf, int hl, int kt, int g) {
    return buf * H_BUF_STRIDE + ((hl * 2 + kt) * 4 + g) * FRAG_BLK;
}
__device__ __forceinline__ int x_off(int slot, int hl, int g) {
    return X_BASE + slot * X_SLOT_STRIDE + (hl * 4 + g) * FRAG_BLK;
}

// split fp32 -> bf16 hi + bf16 lo (lo captures the next 8 mantissa bits; exact residual)
__device__ __forceinline__ void split_bf16(float v, unsigned short &hi, unsigned short &lo) {
    unsigned int b = __float_as_uint(v);
    hi = (unsigned short)(b >> 16);
    float vh = __uint_as_float(b & 0xFFFF0000u);
    lo = (unsigned short)(__float_as_uint(v - vh) >> 16);
}

// gate scale folded into weights: i,f,o -> -log2(e); g -> +2*log2(e)
#define S_SIG  (-1.4426950408889634f)
#define S_TANH ( 2.8853900817779268f)

extern "C" __global__ void __launch_bounds__(BDIM, 1)
seq2seq_kernel(const float* __restrict__ x,
               const float* __restrict__ Wih_e, const float* __restrict__ Whh_e,
               const float* __restrict__ b_e,
               const float* __restrict__ Wih_d, const float* __restrict__ Whh_d,
               const float* __restrict__ b_d,
               const float* __restrict__ Wout, const float* __restrict__ bout,
               float* __restrict__ out)
{
    __shared__ __align__(16) char lds[LDS_BYTES];

    const int tid  = threadIdx.x;
    const int wave = tid >> 6;
    const int lane = tid & 63;
    const int rg   = lane >> 4;          // A/B k-group == C/D row-group
    const int lcol = lane & 15;          // A: M-row | B,C/D: N-col
    const int unit = wave * 16 + lcol;   // hidden unit owned by this lane
    const int row0 = blockIdx.x * ROWS;

    // storage position of h[unit]: k = unit in [0,64)
    const int kt_h = unit >> 5;
    const int g_h  = (unit & 31) >> 3;
    const int j_h  = unit & 7;

    // x staging geometry
    const int xrow = tid >> 4;
    const int xkp  = (tid & 15) * 2;
    const int xg   = xkp >> 3;
    const int xj   = xkp & 7;            // even

    // ---------------- encoder weight fragments (scaled, hi/lo split) ----------------
    short8 whi[3][4], wlo[3][4];
    float  bv[4];
    #pragma unroll
    for (int nt = 0; nt < 4; ++nt) {
        const int n = nt * 64 + unit;
        const float sc = (nt == 2) ? S_TANH : S_SIG;
        bv[nt] = sc * b_e[n];
        #pragma unroll
        for (int kt = 0; kt < 3; ++kt) {
            const int k0 = kt * 32 + rg * 8;
            const float* src = (kt == 0) ? (Wih_e + n * D_IN + k0)
                                         : (Whh_e + n * H_DIM + (k0 - 32));
            #pragma unroll
            for (int j = 0; j < 8; ++j) {
                unsigned short h_, l_;
                split_bf16(sc * src[j], h_, l_);
                whi[kt][nt][j] = (short)h_;
                wlo[kt][nt][j] = (short)l_;
            }
        }
    }

    float c4[4] = {0.f, 0.f, 0.f, 0.f};

    // ---------------- prologue: zero h buf0, stage x[0], prefetch x[1], x[2] ----------------
    for (int i = tid; i < H_BUF_STRIDE / 4; i += BDIM)
        reinterpret_cast<uint32_t*>(lds)[i] = 0u;

    {
        const float2 v = *reinterpret_cast<const float2*>(
            x + ((size_t)(row0 + xrow) * T_SEQ + 0) * D_IN + xkp);
        unsigned short h0, l0, h1, l1;
        split_bf16(v.x, h0, l0); split_bf16(v.y, h1, l1);
        *(uint32_t*)(lds + x_off(0, 0, xg) + xrow * 16 + xj * 2) = (uint32_t)h0 | ((uint32_t)h1 << 16);
        *(uint32_t*)(lds + x_off(0, 1, xg) + xrow * 16 + xj * 2) = (uint32_t)l0 | ((uint32_t)l1 << 16);
    }
    float2 xcur = *reinterpret_cast<const float2*>(
        x + ((size_t)(row0 + xrow) * T_SEQ + 1) * D_IN + xkp);
    float2 xnext = *reinterpret_cast<const float2*>(
        x + ((size_t)(row0 + xrow) * T_SEQ + 2) * D_IN + xkp);

    __syncthreads();

    // pointwise + h-write helper (shared by enc/dec)
    auto pointwise_store = [&](const float4_ (&acc)[4], int nxt_) {
        #pragma unroll
        for (int r = 0; r < 4; ++r) {
            const float ia = __builtin_amdgcn_rcpf(1.0f + __builtin_amdgcn_exp2f(acc[0][r]));
            const float fa = __builtin_amdgcn_rcpf(1.0f + __builtin_amdgcn_exp2f(acc[1][r]));
            const float gr = __builtin_amdgcn_rcpf(1.0f + __builtin_amdgcn_exp2f(acc[2][r]));
            const float ga = __builtin_fmaf(-2.0f, gr, 1.0f);              // tanh(g)
            const float oa = __builtin_amdgcn_rcpf(1.0f + __builtin_amdgcn_exp2f(acc[3][r]));
            const float cv = __builtin_fmaf(fa, c4[r], ia * ga);
            c4[r] = cv;
            const float tt = __builtin_amdgcn_exp2f(cv * -2.8853900817779268f);
            const float rr = __builtin_amdgcn_rcpf(1.0f + tt);             // sigmoid(2c)
            const float hv = __builtin_fmaf(2.0f * oa, rr, -oa);           // o*tanh(c)
            unsigned short hh_, ll_;
            split_bf16(hv, hh_, ll_);
            const int rb = (rg * 4 + r) * 16 + j_h * 2;
            *(unsigned short*)(lds + h_off(nxt_, 0, kt_h, g_h) + rb) = hh_;
            *(unsigned short*)(lds + h_off(nxt_, 1, kt_h, g_h) + rb) = ll_;
        }
    };

    // ================= encoder: 500 steps =================
    int cur = 0;
    for (int t = 0; t < T_SEQ; ++t) {
        const int nxt = cur ^ 1;

        const short8 ah0 = *(const short8*)(lds + x_off(cur, 0, rg) + lcol * 16);
        const short8 al0 = *(const short8*)(lds + x_off(cur, 1, rg) + lcol * 16);
        const short8 ah1 = *(const short8*)(lds + h_off(cur, 0, 0, rg) + lcol * 16);
        const short8 ah2 = *(const short8*)(lds + h_off(cur, 0, 1, rg) + lcol * 16);
        const short8 al1 = *(const short8*)(lds + h_off(cur, 1, 0, rg) + lcol * 16);
        const short8 al2 = *(const short8*)(lds + h_off(cur, 1, 1, rg) + lcol * 16);

        // stage x[t+1] (loaded 2 steps ago) into slot nxt
        if (t + 1 < T_SEQ) {
            unsigned short h0, l0, h1, l1;
            split_bf16(xcur.x, h0, l0); split_bf16(xcur.y, h1, l1);
            *(uint32_t*)(lds + x_off(nxt, 0, xg) + xrow * 16 + xj * 2) = (uint32_t)h0 | ((uint32_t)h1 << 16);
            *(uint32_t*)(lds + x_off(nxt, 1, xg) + xrow * 16 + xj * 2) = (uint32_t)l0 | ((uint32_t)l1 << 16);
        }
        // issue x[t+3]
        float2 newx = {0.f, 0.f};
        if (t + 3 < T_SEQ)
            newx = *reinterpret_cast<const float2*>(
                x + ((size_t)(row0 + xrow) * T_SEQ + (t + 3)) * D_IN + xkp);
        xcur = xnext; xnext = newx;

        // gates = bias + A_hi*B_hi + A_hi*B_lo + A_lo*B_hi  (3 independent acc chains)
        float4_ hh[4], hl4[4], lh[4];
        #pragma unroll
        for (int nt = 0; nt < 4; ++nt) {
            hh[nt]  = (float4_){bv[nt], bv[nt], bv[nt], bv[nt]};
            hl4[nt] = (float4_){0.f, 0.f, 0.f, 0.f};
            lh[nt]  = (float4_){0.f, 0.f, 0.f, 0.f};
        }
        #pragma unroll
        for (int nt = 0; nt < 4; ++nt) {
            hh[nt]  = __builtin_amdgcn_mfma_f32_16x16x32_bf16(ah0, whi[0][nt], hh[nt], 0, 0, 0);
            hh[nt]  = __builtin_amdgcn_mfma_f32_16x16x32_bf16(ah1, whi[1][nt], hh[nt], 0, 0, 0);
            hh[nt]  = __builtin_amdgcn_mfma_f32_16x16x32_bf16(ah2, whi[2][nt], hh[nt], 0, 0, 0);
            hl4[nt] = __builtin_amdgcn_mfma_f32_16x16x32_bf16(ah0, wlo[0][nt], hl4[nt], 0, 0, 0);
            hl4[nt] = __builtin_amdgcn_mfma_f32_16x16x32_bf16(ah1, wlo[1][nt], hl4[nt], 0, 0, 0);
            hl4[nt] = __builtin_amdgcn_mfma_f32_16x16x32_bf16(ah2, wlo[2][nt], hl4[nt], 0, 0, 0);
            lh[nt]  = __builtin_amdgcn_mfma_f32_16x16x32_bf16(al0, whi[0][nt], lh[nt], 0, 0, 0);
            lh[nt]  = __builtin_amdgcn_mfma_f32_16x16x32_bf16(al1, whi[1][nt], lh[nt], 0, 0, 0);
            lh[nt]  = __builtin_amdgcn_mfma_f32_16x16x32_bf16(al2, whi[2][nt], lh[nt], 0, 0, 0);
        }
        float4_ acc[4];
        #pragma unroll
        for (int nt = 0; nt < 4; ++nt) acc[nt] = hh[nt] + hl4[nt] + lh[nt];

        pointwise_store(acc, nxt);
        __syncthreads();
        cur = nxt;
    }

    // ================= decoder =================
    // step 0: input is zeros -> gates = h @ Whh_d^T + b_d
    #pragma unroll
    for (int nt = 0; nt < 4; ++nt) {
        const int n = nt * 64 + unit;
        const float sc = (nt == 2) ? S_TANH : S_SIG;
        bv[nt] = sc * b_d[n];
        #pragma unroll
        for (int kt = 0; kt < 2; ++kt) {
            const float* src = Whh_d + n * H_DIM + kt * 32 + rg * 8;
            #pragma unroll
            for (int j = 0; j < 8; ++j) {
                unsigned short h_, l_;
                split_bf16(sc * src[j], h_, l_);
                whi[kt][nt][j] = (short)h_;
                wlo[kt][nt][j] = (short)l_;
            }
        }
    }
    {
        const short8 ah0 = *(const short8*)(lds + h_off(cur, 0, 0, rg) + lcol * 16);
        const short8 ah1 = *(const short8*)(lds + h_off(cur, 0, 1, rg) + lcol * 16);
        const short8 al0 = *(const short8*)(lds + h_off(cur, 1, 0, rg) + lcol * 16);
        const short8 al1 = *(const short8*)(lds + h_off(cur, 1, 1, rg) + lcol * 16);
        float4_ hh[4], hl4[4], lh[4];
        #pragma unroll
        for (int nt = 0; nt < 4; ++nt) {
            hh[nt]  = (float4_){bv[nt], bv[nt], bv[nt], bv[nt]};
            hl4[nt] = (float4_){0.f, 0.f, 0.f, 0.f};
            lh[nt]  = (float4_){0.f, 0.f, 0.f, 0.f};
        }
        #pragma unroll
        for (int nt = 0; nt < 4; ++nt) {
            hh[nt]  = __builtin_amdgcn_mfma_f32_16x16x32_bf16(ah0, whi[0][nt], hh[nt], 0, 0, 0);
            hh[nt]  = __builtin_amdgcn_mfma_f32_16x16x32_bf16(ah1, whi[1][nt], hh[nt], 0, 0, 0);
            hl4[nt] = __builtin_amdgcn_mfma_f32_16x16x32_bf16(ah0, wlo[0][nt], hl4[nt], 0, 0, 0);
            hl4[nt] = __builtin_amdgcn_mfma_f32_16x16x32_bf16(ah1, wlo[1][nt], hl4[nt], 0, 0, 0);
            lh[nt]  = __builtin_amdgcn_mfma_f32_16x16x32_bf16(al0, whi[0][nt], lh[nt], 0, 0, 0);
            lh[nt]  = __builtin_amdgcn_mfma_f32_16x16x32_bf16(al1, whi[1][nt], lh[nt], 0, 0, 0);
        }
        float4_ acc[4];
        #pragma unroll
        for (int nt = 0; nt < 4; ++nt) acc[nt] = hh[nt] + hl4[nt] + lh[nt];
        pointwise_store(acc, cur ^ 1);
        __syncthreads();
        cur ^= 1;
    }

    // combined decoder weights: Wcomb = Whh_d + Wih_d @ Wout ; bcomb = b_d + Wih_d @ bout
    #pragma unroll
    for (int nt = 0; nt < 4; ++nt) {
        const int n = nt * 64 + unit;
        const float sc = (nt == 2) ? S_TANH : S_SIG;
        float wihr[32];
        #pragma unroll
        for (int d = 0; d < 32; ++d) wihr[d] = Wih_d[n * D_IN + d];
        float bb = b_d[n];
        #pragma unroll
        for (int d = 0; d < 32; ++d) bb += wihr[d] * bout[d];
        bv[nt] = sc * bb;
        #pragma unroll
        for (int kt = 0; kt < 2; ++kt) {
            #pragma unroll
            for (int j = 0; j < 8; ++j) {
                const int k = kt * 32 + rg * 8 + j;
                float w = Whh_d[n * H_DIM + k];
                #pragma unroll
                for (int d = 0; d < 32; ++d) w += wihr[d] * Wout[d * H_DIM + k];
                unsigned short h_, l_;
                split_bf16(sc * w, h_, l_);
                whi[kt][nt][j] = (short)h_;
                wlo[kt][nt][j] = (short)l_;
            }
        }
    }
    // Wout fragments for the out side-computation (waves 0,1)
    short8 wohi[2], wolo[2];
    float  bo = 0.0f;
    const int ocol = (wave & 1) * 16 + lcol;
    if (wave < 2) {
        bo = bout[ocol];
        #pragma unroll
        for (int kt = 0; kt < 2; ++kt) {
            const float* src = Wout + (size_t)ocol * H_DIM + kt * 32 + rg * 8;
            #pragma unroll
            for (int j = 0; j < 8; ++j) {
                unsigned short h_, l_;
                split_bf16(src[j], h_, l_);
                wohi[kt][j] = (short)h_;
                wolo[kt][j] = (short)l_;
            }
        }
    }

    // steps 1..499: gates via Wcomb; out_{s-1} = h_s @ Wout^T (off critical path)
    for (int s = 1; s < T_SEQ; ++s) {
        const int nxt = cur ^ 1;
        const short8 ah0 = *(const short8*)(lds + h_off(cur, 0, 0, rg) + lcol * 16);
        const short8 ah1 = *(const short8*)(lds + h_off(cur, 0, 1, rg) + lcol * 16);
        const short8 al0 = *(const short8*)(lds + h_off(cur, 1, 0, rg) + lcol * 16);
        const short8 al1 = *(const short8*)(lds + h_off(cur, 1, 1, rg) + lcol * 16);

        float4_ hh[4], hl4[4], lh[4];
        #pragma unroll
        for (int nt = 0; nt < 4; ++nt) {
            hh[nt]  = (float4_){bv[nt], bv[nt], bv[nt], bv[nt]};
            hl4[nt] = (float4_){0.f, 0.f, 0.f, 0.f};
            lh[nt]  = (float4_){0.f, 0.f, 0.f, 0.f};
        }
        #pragma unroll
        for (int nt = 0; nt < 4; ++nt) {
            hh[nt]  = __builtin_amdgcn_mfma_f32_16x16x32_bf16(ah0, whi[0][nt], hh[nt], 0, 0, 0);
            hh[nt]  = __builtin_amdgcn_mfma_f32_16x16x32_bf16(ah1, whi[1][nt], hh[nt], 0, 0, 0);
            hl4[nt] = __builtin_amdgcn_mfma_f32_16x16x32_bf16(ah0, wlo[0][nt], hl4[nt], 0, 0, 0);
            hl4[nt] = __builtin_amdgcn_mfma_f32_16x16x32_bf16(ah1, wlo[1][nt], hl4[nt], 0, 0, 0);
            lh[nt]  = __builtin_amdgcn_mfma_f32_16x16x32_bf16(al0, whi[0][nt], lh[nt], 0, 0, 0);
            lh[nt]  = __builtin_amdgcn_mfma_f32_16x16x32_bf16(al1, whi[1][nt], lh[nt], 0, 0, 0);
        }

        // out_{s-1} from the same A-frags (waves 0,1 only)
        if (wave < 2) {
            float4_ ohh = (float4_){bo, bo, bo, bo};
            float4_ ore = (float4_){0.f, 0.f, 0.f, 0.f};
            ohh = __builtin_amdgcn_mfma_f32_16x16x32_bf16(ah0, wohi[0], ohh, 0, 0, 0);
            ohh = __builtin_amdgcn_mfma_f32_16x16x32_bf16(ah1, wohi[1], ohh, 0, 0, 0);
            ore = __builtin_amdgcn_mfma_f32_16x16x32_bf16(ah0, wolo[0], ore, 0, 0, 0);
            ore = __builtin_amdgcn_mfma_f32_16x16x32_bf16(ah1, wolo[1], ore, 0, 0, 0);
            ore = __builtin_amdgcn_mfma_f32_16x16x32_bf16(al0, wohi[0], ore, 0, 0, 0);
            ore = __builtin_amdgcn_mfma_f32_16x16x32_bf16(al1, wohi[1], ore, 0, 0, 0);
            const float4_ ov = ohh + ore;
            #pragma unroll
            for (int r = 0; r < 4; ++r)
                out[((size_t)(row0 + rg * 4 + r) * T_SEQ + (s - 1)) * D_IN + ocol] = ov[r];
        }

        float4_ acc[4];
        #pragma unroll
        for (int nt = 0; nt < 4; ++nt) acc[nt] = hh[nt] + hl4[nt] + lh[nt];
        pointwise_store(acc, nxt);
        __syncthreads();
        cur = nxt;
    }

    // tail: out_499 = h_500 @ Wout^T
    if (wave < 2) {
        const short8 ah0 = *(const short8*)(lds + h_off(cur, 0, 0, rg) + lcol * 16);
        const short8 ah1 = *(const short8*)(lds + h_off(cur, 0, 1, rg) + lcol * 16);
        const short8 al0 = *(const short8*)(lds + h_off(cur, 1, 0, rg) + lcol * 16);
        const short8 al1 = *(const short8*)(lds + h_off(cur, 1, 1, rg) + lcol * 16);
        float4_ ohh = (float4_){bo, bo, bo, bo};
        float4_ ore = (float4_){0.f, 0.f, 0.f, 0.f};
        ohh = __builtin_amdgcn_mfma_f32_16x16x32_bf16(ah0, wohi[0], ohh, 0, 0, 0);
        ohh = __builtin_amdgcn_mfma_f32_16x16x32_bf16(ah1, wohi[1], ohh, 0, 0, 0);
        ore = __builtin_amdgcn_mfma_f32_16x16x32_bf16(ah0, wolo[0], ore, 0, 0, 0);
        ore = __builtin_amdgcn_mfma_f32_16x16x32_bf16(ah1, wolo[1], ore, 0, 0, 0);
        ore = __builtin_amdgcn_mfma_f32_16x16x32_bf16(al0, wohi[0], ore, 0, 0, 0);
        ore = __builtin_amdgcn_mfma_f32_16x16x32_bf16(al1, wohi[1], ore, 0, 0, 0);
        const float4_ ov = ohh + ore;
        #pragma unroll
        for (int r = 0; r < 4; ++r)
            out[((size_t)(row0 + rg * 4 + r) * T_SEQ + (T_SEQ - 1)) * D_IN + ocol] = ov[r];
    }
}

extern "C" void kernel_launch(void* const* d_in, const int* in_sizes, int n_in,
                              void* d_out, int out_size, void* d_ws, size_t ws_size,
                              hipStream_t stream) {
    (void)n_in; (void)d_ws; (void)ws_size; (void)out_size;
    const float* x     = (const float*)d_in[0];
    const float* Wih_e = (const float*)d_in[1];
    const float* Whh_e = (const float*)d_in[2];
    const float* b_e   = (const float*)d_in[3];
    const float* Wih_d = (const float*)d_in[4];
    const float* Whh_d = (const float*)d_in[5];
    const float* b_d   = (const float*)d_in[6];
    const float* Wout  = (const float*)d_in[7];
    const float* bout  = (const float*)d_in[8];
    float* out = (float*)d_out;

    const int B = in_sizes[0] / (T_SEQ * D_IN);   // 4096
    dim3 grid(B / ROWS), block(BDIM);
    hipLaunchKernelGGL(seq2seq_kernel, grid, block, 0, stream,
                       x, Wih_e, Whh_e, b_e, Wih_d, Whh_d, b_d, Wout, bout, out);
}

// Round 4
// 706.581 us; speedup vs baseline: 1.6393x; 1.2017x over previous
//
#include <hip/hip_runtime.h>
#include <stdint.h>

#define T_SEQ 500
#define D_IN  32
#define H_DIM 64
#define BDIM  512

using short8  = __attribute__((ext_vector_type(8))) short;  // 8 bf16
using float4_ = __attribute__((ext_vector_type(4))) float;  // MFMA C/D frag

#define MFMA16(a,b,c) __builtin_amdgcn_mfma_f32_16x16x32_bf16((a),(b),(c),0,0,0)

// ---------------- LDS geometry (bytes) ----------------
// frag block = 16 rows x 16B + 16B pad
#define FRAG_BLK 272
#define HOFF(buf,hl,kt,g) ((((((buf)*2+(hl))*2+(kt))*4)+(g))*FRAG_BLK)
#define H_TOTAL  (2*2*2*4*FRAG_BLK)              // 8704
#define XOFF(slot,hl,g)   (H_TOTAL + ((((slot)*2+(hl))*4)+(g))*FRAG_BLK)
#define LDS_BYTES (H_TOTAL + 2*2*4*FRAG_BLK)     // 13056

// ---------------- workspace layout (bytes) ----------------
#define WS_ENC   0                                // [kt3][w8][tl2][hl2][lane64] short8
#define WS_DEC0  (WS_ENC  + 3*8*2*2*64*16)        // 98304
#define WS_COMB  (WS_DEC0 + 2*8*2*2*64*16)        // 163840
#define WS_OUT   (WS_COMB + 2*8*2*2*64*16)        // 229376 : [kt2][tl2][hl2][lane64]
#define WS_BENC  (WS_OUT  + 2*2*2*64*16)          // 237568 : [w8][tl2][lane64] f32
#define WS_BDEC0 (WS_BENC  + 8*2*64*4)            // 241664
#define WS_BCOMB (WS_BDEC0 + 8*2*64*4)            // 245760
#define WS_BOUT  (WS_BCOMB + 8*2*64*4)            // 249856 : [tl2][lane64] f32
// total 250368 bytes

// gate scale folded into weights: i,f,o -> -log2(e); g -> +2*log2(e)
#define S_SIG  (-1.4426950408889634f)
#define S_TANH ( 2.8853900817779268f)

__device__ __forceinline__ void split_bf16(float v, unsigned short &hi, unsigned short &lo) {
    unsigned int b = __float_as_uint(v);
    hi = (unsigned short)(b >> 16);
    float vh = __uint_as_float(b & 0xFFFF0000u);
    lo = (unsigned short)(__float_as_uint(v - vh) >> 16);
}

// ==================== prep kernel: split weights into B-fragments ====================
// col mapping within wave w: tile tl, col c(0..15): gate = tl*2 + (c>>3), unit = w*8 + (c&7)
// frag element j of lane: k = (lane>>4)*8 + j  (same k-map as A side)
__global__ void __launch_bounds__(512)
prep_kernel(const float* __restrict__ Wih_e, const float* __restrict__ Whh_e,
            const float* __restrict__ b_e,
            const float* __restrict__ Wih_d, const float* __restrict__ Whh_d,
            const float* __restrict__ b_d,
            const float* __restrict__ Wout, const float* __restrict__ bout,
            char* __restrict__ ws)
{
    const int tid  = blockIdx.x * blockDim.x + threadIdx.x;
    const int nthr = gridDim.x * blockDim.x;

    // encoder gate fragments: slots (kt3, w8, tl2, lane64)  [s: lane 5:0 | tl 6 | w 9:7 | kt 11:10]
    for (int s = tid; s < 3*8*2*64; s += nthr) {
        const int lane = s & 63, tl = (s >> 6) & 1, w = (s >> 7) & 7, kt = s >> 10;
        const int c = lane & 15, rg = lane >> 4;
        const int gate = tl*2 + (c >> 3);
        const int unit = w*8 + (c & 7);
        const int n = gate*64 + unit;
        const float sc = (gate == 2) ? S_TANH : S_SIG;
        short8 hi8, lo8;
        #pragma unroll
        for (int j = 0; j < 8; ++j) {
            const int k = kt*32 + rg*8 + j;
            const float wv = sc * ((k < 32) ? Wih_e[n*D_IN + k] : Whh_e[n*H_DIM + k - 32]);
            unsigned short h_, l_; split_bf16(wv, h_, l_);
            hi8[j] = (short)h_; lo8[j] = (short)l_;
        }
        const size_t base = (size_t)((((kt*8+w)*2+tl)*2+0)*64 + lane) * 16;
        *(short8*)(ws + WS_ENC + base)           = hi8;
        *(short8*)(ws + WS_ENC + base + 64*16)   = lo8;
    }

    // decoder step-0 (Whh_d) and combined (Whh_d + Wih_d@Wout): slots (kt2, w8, tl2, lane64)
    // [s: lane 5:0 | tl 6 | w 9:7 | kt 10]  (BUGFIX r3: kt was s>>9, aliasing w's top bit)
    for (int s = tid; s < 2*8*2*64; s += nthr) {
        const int lane = s & 63, tl = (s >> 6) & 1, w = (s >> 7) & 7, kt = s >> 10;
        const int c = lane & 15, rg = lane >> 4;
        const int gate = tl*2 + (c >> 3);
        const int unit = w*8 + (c & 7);
        const int n = gate*64 + unit;
        const float sc = (gate == 2) ? S_TANH : S_SIG;
        short8 h0v, l0v, hcv, lcv;
        #pragma unroll
        for (int j = 0; j < 8; ++j) {
            const int k = kt*32 + rg*8 + j;
            const float w0 = Whh_d[n*H_DIM + k];
            float a = w0;
            for (int d = 0; d < 32; ++d) a += Wih_d[n*D_IN + d] * Wout[d*H_DIM + k];
            unsigned short h_, l_;
            split_bf16(sc * w0, h_, l_); h0v[j] = (short)h_; l0v[j] = (short)l_;
            split_bf16(sc * a,  h_, l_); hcv[j] = (short)h_; lcv[j] = (short)l_;
        }
        const size_t base = (size_t)((((kt*8+w)*2+tl)*2+0)*64 + lane) * 16;
        *(short8*)(ws + WS_DEC0 + base)         = h0v;
        *(short8*)(ws + WS_DEC0 + base + 64*16) = l0v;
        *(short8*)(ws + WS_COMB + base)         = hcv;
        *(short8*)(ws + WS_COMB + base + 64*16) = lcv;
    }

    // Wout fragments: slots (kt2, tl2, lane64); col = tl*16 + (lane&15)
    for (int s = tid; s < 2*2*64; s += nthr) {
        const int lane = s & 63, tl = (s >> 6) & 1, kt = s >> 7;
        const int rg = lane >> 4;
        const int ocol = tl*16 + (lane & 15);
        short8 hi8, lo8;
        #pragma unroll
        for (int j = 0; j < 8; ++j) {
            const int k = kt*32 + rg*8 + j;
            unsigned short h_, l_; split_bf16(Wout[ocol*H_DIM + k], h_, l_);
            hi8[j] = (short)h_; lo8[j] = (short)l_;
        }
        const size_t base = (size_t)(((kt*2+tl)*2+0)*64 + lane) * 16;
        *(short8*)(ws + WS_OUT + base)         = hi8;
        *(short8*)(ws + WS_OUT + base + 64*16) = lo8;
    }

    // biases: slots (w8, tl2, lane64)
    for (int s = tid; s < 8*2*64; s += nthr) {
        const int lane = s & 63, tl = (s >> 6) & 1, w = s >> 7;
        const int c = lane & 15;
        const int gate = tl*2 + (c >> 3);
        const int unit = w*8 + (c & 7);
        const int n = gate*64 + unit;
        const float sc = (gate == 2) ? S_TANH : S_SIG;
        float a = b_d[n];
        for (int d = 0; d < 32; ++d) a += Wih_d[n*D_IN + d] * bout[d];
        ((float*)(ws + WS_BENC))[s]  = sc * b_e[n];
        ((float*)(ws + WS_BDEC0))[s] = sc * b_d[n];
        ((float*)(ws + WS_BCOMB))[s] = sc * a;
    }
    for (int s = tid; s < 2*64; s += nthr)
        ((float*)(ws + WS_BOUT))[s] = bout[(s >> 6)*16 + (s & 15)];
}

// ==================== main kernel ====================
extern "C" __global__ void __launch_bounds__(BDIM, 2)
seq2seq_main(const float* __restrict__ x, const char* __restrict__ ws,
             float* __restrict__ out)
{
    __shared__ __align__(16) char lds[LDS_BYTES];

    const int tid  = threadIdx.x;
    const int w    = tid >> 6;
    const int lane = tid & 63;
    const int rg   = lane >> 4;
    const int lcol = lane & 15;
    const int sel  = lcol >> 3;            // 0: own gate i/g, rows rg*4+{0,1}; 1: f/o, rows rg*4+{2,3}
    const int row0 = blockIdx.x * 16;

    const int KT_H = w >> 2, G_H = w & 3, JH = lcol & 7;   // h[unit=w*8+(lcol&7)] position
    const int xr = tid >> 5, xk = tid & 31, xg = xk >> 3, xj = xk & 7;

    // ---- encoder weight fragments + biases ----
    short8 whi[3][2], wlo[3][2];
    float  bias[2];
    #pragma unroll
    for (int kt = 0; kt < 3; ++kt)
        #pragma unroll
        for (int tl = 0; tl < 2; ++tl) {
            const size_t base = (size_t)((((kt*8+w)*2+tl)*2+0)*64 + lane) * 16;
            whi[kt][tl] = *(const short8*)(ws + WS_ENC + base);
            wlo[kt][tl] = *(const short8*)(ws + WS_ENC + base + 64*16);
        }
    #pragma unroll
    for (int tl = 0; tl < 2; ++tl)
        bias[tl] = ((const float*)(ws + WS_BENC))[(w*2+tl)*64 + lane];

    float c2[2] = {0.f, 0.f};

    // zero h buf0 (first 4352 bytes)
    for (int i = tid; i < 4352/4; i += BDIM) ((uint32_t*)lds)[i] = 0u;

    // stage x[0], prefetch x[1]
    {
        const float v0 = x[((size_t)(row0 + xr)*T_SEQ + 0)*D_IN + xk];
        unsigned short h_, l_; split_bf16(v0, h_, l_);
        *(unsigned short*)(lds + XOFF(0,0,xg) + xr*16 + xj*2) = h_;
        *(unsigned short*)(lds + XOFF(0,1,xg) + xr*16 + xj*2) = l_;
    }
    float xreg = x[((size_t)(row0 + xr)*T_SEQ + 1)*D_IN + xk];
    __syncthreads();

    auto swz = [](float v) {   // lane ^ 8 exchange (in-wave, partner has other gate)
        return __int_as_float(__builtin_amdgcn_ds_swizzle(__float_as_int(v), 0x201F));
    };

    // exchange + pointwise + h-write (2 rows per lane)
    auto pw = [&](float4_ a0, float4_ a1, int nxt) {
        float sw0[4], sw1[4];
        #pragma unroll
        for (int r = 0; r < 4; ++r) { sw0[r] = swz(a0[r]); sw1[r] = swz(a1[r]); }
        #pragma unroll
        for (int si = 0; si < 2; ++si) {
            const float ip = sel ? sw0[2+si] : a0[si];
            const float fp = sel ? a0[2+si] : sw0[si];
            const float gp = sel ? sw1[2+si] : a1[si];
            const float op = sel ? a1[2+si] : sw1[si];
            const float ia = __builtin_amdgcn_rcpf(1.0f + __builtin_amdgcn_exp2f(ip));
            const float fa = __builtin_amdgcn_rcpf(1.0f + __builtin_amdgcn_exp2f(fp));
            const float ga = __builtin_fmaf(-2.0f,
                              __builtin_amdgcn_rcpf(1.0f + __builtin_amdgcn_exp2f(gp)), 1.0f);
            const float oa = __builtin_amdgcn_rcpf(1.0f + __builtin_amdgcn_exp2f(op));
            const float cv = __builtin_fmaf(fa, c2[si], ia * ga);
            c2[si] = cv;
            const float tt = __builtin_amdgcn_exp2f(cv * -2.8853900817779268f);
            const float hv = __builtin_fmaf(2.0f * oa,
                              __builtin_amdgcn_rcpf(1.0f + tt), -oa);
            unsigned short hh_, ll_; split_bf16(hv, hh_, ll_);
            const int rb = (rg*4 + sel*2 + si)*16 + JH*2;
            *(unsigned short*)(lds + HOFF(nxt,0,KT_H,G_H) + rb) = hh_;
            *(unsigned short*)(lds + HOFF(nxt,1,KT_H,G_H) + rb) = ll_;
        }
    };

    auto ldh = [&](int buf, int hl, int kt) {
        return *(const short8*)(lds + HOFF(buf,hl,kt,rg) + lcol*16);
    };

    // ---------------- encoder: 500 steps ----------------
    auto enc_step = [&](int CUR, int t) {
        const int NXT = CUR ^ 1;
        const short8 axh = *(const short8*)(lds + XOFF(CUR,0,rg) + lcol*16);
        const short8 axl = *(const short8*)(lds + XOFF(CUR,1,rg) + lcol*16);
        const short8 ah0 = ldh(CUR,0,0), ah1 = ldh(CUR,0,1);
        const short8 al0 = ldh(CUR,1,0), al1 = ldh(CUR,1,1);

        const float xold = xreg;
        xreg = (t + 2 < T_SEQ) ? x[((size_t)(row0 + xr)*T_SEQ + (t+2))*D_IN + xk] : 0.f;
        if (t + 1 < T_SEQ) {
            unsigned short h_, l_; split_bf16(xold, h_, l_);
            *(unsigned short*)(lds + XOFF(NXT,0,xg) + xr*16 + xj*2) = h_;
            *(unsigned short*)(lds + XOFF(NXT,1,xg) + xr*16 + xj*2) = l_;
        }

        float4_ acc[2];
        #pragma unroll
        for (int tl = 0; tl < 2; ++tl) {
            float4_ m = {bias[tl], bias[tl], bias[tl], bias[tl]};
            m = MFMA16(axh, whi[0][tl], m);
            m = MFMA16(ah0, whi[1][tl], m);
            m = MFMA16(ah1, whi[2][tl], m);
            float4_ rs = {0.f, 0.f, 0.f, 0.f};
            rs = MFMA16(axh, wlo[0][tl], rs);
            rs = MFMA16(ah0, wlo[1][tl], rs);
            rs = MFMA16(ah1, wlo[2][tl], rs);
            rs = MFMA16(axl, whi[0][tl], rs);
            rs = MFMA16(al0, whi[1][tl], rs);
            rs = MFMA16(al1, whi[2][tl], rs);
            acc[tl] = m + rs;
        }
        pw(acc[0], acc[1], NXT);
        __syncthreads();
    };

    int t = 0;
    for (int it = 0; it < 250; ++it) { enc_step(0, t); ++t; enc_step(1, t); ++t; }
    // h_enc now in buf 0

    // ---------------- decoder step 0 (input = zeros; Whh_d only) ----------------
    #pragma unroll
    for (int kt = 0; kt < 2; ++kt)
        #pragma unroll
        for (int tl = 0; tl < 2; ++tl) {
            const size_t base = (size_t)((((kt*8+w)*2+tl)*2+0)*64 + lane) * 16;
            whi[kt][tl] = *(const short8*)(ws + WS_DEC0 + base);
            wlo[kt][tl] = *(const short8*)(ws + WS_DEC0 + base + 64*16);
        }
    #pragma unroll
    for (int tl = 0; tl < 2; ++tl)
        bias[tl] = ((const float*)(ws + WS_BDEC0))[(w*2+tl)*64 + lane];
    {
        const short8 a0 = ldh(0,0,0), a1 = ldh(0,0,1);
        const short8 q0 = ldh(0,1,0), q1 = ldh(0,1,1);
        float4_ acc[2];
        #pragma unroll
        for (int tl = 0; tl < 2; ++tl) {
            float4_ m = {bias[tl], bias[tl], bias[tl], bias[tl]};
            m = MFMA16(a0, whi[0][tl], m);
            m = MFMA16(a1, whi[1][tl], m);
            float4_ rs = {0.f, 0.f, 0.f, 0.f};
            rs = MFMA16(a0, wlo[0][tl], rs);
            rs = MFMA16(a1, wlo[1][tl], rs);
            rs = MFMA16(q0, whi[0][tl], rs);
            rs = MFMA16(q1, whi[1][tl], rs);
            acc[tl] = m + rs;
        }
        pw(acc[0], acc[1], 1);
        __syncthreads();
    }

    // ---------------- decoder steps 1..499 (Wcomb; out as side-effect) ----------------
    #pragma unroll
    for (int kt = 0; kt < 2; ++kt)
        #pragma unroll
        for (int tl = 0; tl < 2; ++tl) {
            const size_t base = (size_t)((((kt*8+w)*2+tl)*2+0)*64 + lane) * 16;
            whi[kt][tl] = *(const short8*)(ws + WS_COMB + base);
            wlo[kt][tl] = *(const short8*)(ws + WS_COMB + base + 64*16);
        }
    #pragma unroll
    for (int tl = 0; tl < 2; ++tl)
        bias[tl] = ((const float*)(ws + WS_BCOMB))[(w*2+tl)*64 + lane];

    const bool ow  = (w == 0) || (w == 4);
    const int  tlo = (w == 0) ? 0 : 1;
    const int  ocol = tlo*16 + lcol;
    short8 woh[2] = {}, wol[2] = {};
    float  bo = 0.f;
    if (ow) {
        #pragma unroll
        for (int kt = 0; kt < 2; ++kt) {
            const size_t base = (size_t)(((kt*2+tlo)*2+0)*64 + lane) * 16;
            woh[kt] = *(const short8*)(ws + WS_OUT + base);
            wol[kt] = *(const short8*)(ws + WS_OUT + base + 64*16);
        }
        bo = ((const float*)(ws + WS_BOUT))[tlo*64 + lane];
    }

    auto dec_step = [&](int CUR, int s) {
        const short8 a0 = ldh(CUR,0,0), a1 = ldh(CUR,0,1);
        const short8 q0 = ldh(CUR,1,0), q1 = ldh(CUR,1,1);
        float4_ acc[2];
        #pragma unroll
        for (int tl = 0; tl < 2; ++tl) {
            float4_ m = {bias[tl], bias[tl], bias[tl], bias[tl]};
            m = MFMA16(a0, whi[0][tl], m);
            m = MFMA16(a1, whi[1][tl], m);
            float4_ rs = {0.f, 0.f, 0.f, 0.f};
            rs = MFMA16(a0, wlo[0][tl], rs);
            rs = MFMA16(a1, wlo[1][tl], rs);
            rs = MFMA16(q0, whi[0][tl], rs);
            rs = MFMA16(q1, whi[1][tl], rs);
            acc[tl] = m + rs;
        }
        if (ow) {   // out_{s-1} = h_s @ Wout^T + bout
            float4_ om = {bo, bo, bo, bo};
            om = MFMA16(a0, woh[0], om);
            om = MFMA16(a1, woh[1], om);
            float4_ os = {0.f, 0.f, 0.f, 0.f};
            os = MFMA16(a0, wol[0], os);
            os = MFMA16(a1, wol[1], os);
            os = MFMA16(q0, woh[0], os);
            os = MFMA16(q1, woh[1], os);
            const float4_ ov = om + os;
            #pragma unroll
            for (int r = 0; r < 4; ++r)
                out[((size_t)(row0 + rg*4 + r)*T_SEQ + (s-1))*D_IN + ocol] = ov[r];
        }
        pw(acc[0], acc[1], CUR ^ 1);
        __syncthreads();
    };

    int s = 1;
    for (int it = 0; it < 249; ++it) { dec_step(1, s); ++s; dec_step(0, s); ++s; }
    dec_step(1, s);   // s = 499; writes h_500 into buf 0

    // tail: out_499 = h_500 @ Wout^T + bout
    if (ow) {
        const short8 a0 = ldh(0,0,0), a1 = ldh(0,0,1);
        const short8 q0 = ldh(0,1,0), q1 = ldh(0,1,1);
        float4_ om = {bo, bo, bo, bo};
        om = MFMA16(a0, woh[0], om);
        om = MFMA16(a1, woh[1], om);
        float4_ os = {0.f, 0.f, 0.f, 0.f};
        os = MFMA16(a0, wol[0], os);
        os = MFMA16(a1, wol[1], os);
        os = MFMA16(q0, woh[0], os);
        os = MFMA16(q1, woh[1], os);
        const float4_ ov = om + os;
        #pragma unroll
        for (int r = 0; r < 4; ++r)
            out[((size_t)(row0 + rg*4 + r)*T_SEQ + (T_SEQ-1))*D_IN + ocol] = ov[r];
    }
}

extern "C" void kernel_launch(void* const* d_in, const int* in_sizes, int n_in,
                              void* d_out, int out_size, void* d_ws, size_t ws_size,
                              hipStream_t stream) {
    (void)n_in; (void)ws_size; (void)out_size;
    const float* x     = (const float*)d_in[0];
    const float* Wih_e = (const float*)d_in[1];
    const float* Whh_e = (const float*)d_in[2];
    const float* b_e   = (const float*)d_in[3];
    const float* Wih_d = (const float*)d_in[4];
    const float* Whh_d = (const float*)d_in[5];
    const float* b_d   = (const float*)d_in[6];
    const float* Wout  = (const float*)d_in[7];
    const float* bout  = (const float*)d_in[8];
    float* out = (float*)d_out;

    const int B = in_sizes[0] / (T_SEQ * D_IN);   // 4096

    hipLaunchKernelGGL(prep_kernel, dim3(8), dim3(512), 0, stream,
                       Wih_e, Whh_e, b_e, Wih_d, Whh_d, b_d, Wout, bout, (char*)d_ws);
    hipLaunchKernelGGL(seq2seq_main, dim3(B / 16), dim3(BDIM), 0, stream,
                       x, (const char*)d_ws, out);
}